// Round 1
// baseline (3354.861 us; speedup 1.0000x reference)
//
#include <hip/hip_runtime.h>
#include <stdint.h>

#define D 2560
#define NH 64
#define HD 40
#define TE_ 512
#define FFD 10240
#define TENC 128
#define THID 1024
#define SEQ 1152   // TENC + THID

typedef __bf16 bf16_t;
typedef __bf16 bf16x8 __attribute__((ext_vector_type(8)));
typedef float  f32x4  __attribute__((ext_vector_type(4)));

__device__ __forceinline__ void gld_lds16(const void* g, void* l) {
  __builtin_amdgcn_global_load_lds((__attribute__((address_space(1))) void*)(g),
                                   (__attribute__((address_space(3))) void*)(l), 16, 0, 0);
}

// ---------------- ada: emb = time_embed @ ada_w + ada_b  (1x512 @ 512x30720)
__global__ void ada_gemv(const float* __restrict__ te, const float* __restrict__ aw,
                         const float* __restrict__ ab, float* __restrict__ emb) {
  int j = blockIdx.x * 128 + threadIdx.x;
  float acc = ab[j];
  #pragma unroll 8
  for (int k = 0; k < TE_; ++k) acc = fmaf(te[k], aw[(size_t)k * (12 * D) + j], acc);
  emb[j] = acc;
}

// ---------------- LN + adaLN modulation -> bf16 x  (rows 0..127 = encoder)
__global__ void ln_mod(const float* __restrict__ hid, const float* __restrict__ enc,
                       const float* __restrict__ emb, bf16_t* __restrict__ out,
                       int shift_h, int scale_h, int shift_e, int scale_e) {
  int row = blockIdx.x, tid = threadIdx.x;
  const float *src, *sc, *sh;
  if (row < TENC) { src = enc + (size_t)row * D;          sc = emb + scale_e * D; sh = emb + shift_e * D; }
  else            { src = hid + (size_t)(row - TENC) * D; sc = emb + scale_h * D; sh = emb + shift_h * D; }
  float v[10], s = 0.f, s2 = 0.f;
  #pragma unroll
  for (int i = 0; i < 10; ++i) { v[i] = src[tid + i * 256]; s += v[i]; s2 += v[i] * v[i]; }
  #pragma unroll
  for (int o = 32; o > 0; o >>= 1) { s += __shfl_down(s, o); s2 += __shfl_down(s2, o); }
  __shared__ float red[8];
  int wv = tid >> 6, ln = tid & 63;
  if (ln == 0) { red[wv] = s; red[4 + wv] = s2; }
  __syncthreads();
  s  = red[0] + red[1] + red[2] + red[3];
  s2 = red[4] + red[5] + red[6] + red[7];
  float mean = s * (1.f / D);
  float rstd = rsqrtf(s2 * (1.f / D) - mean * mean + 1e-5f);
  #pragma unroll
  for (int i = 0; i < 10; ++i) {
    int c = tid + i * 256;
    out[(size_t)row * D + c] = (bf16_t)((v[i] - mean) * rstd * (1.f + sc[c]) + sh[c]);
  }
}

// ---------------- GEMM: C[M=1152][N] = A_bf16[M][K] @ W_f32[K][N] + bias, fused epilogues
// EPI 0: scatter to head layout [h][row][d] f32 (QKV)
// EPI 1: gelu(tanh) -> bf16 row-major (FF1)
// EPI 2: residual + gate -> f32 (O-proj -> h1/e1, FF2 -> d_out)
template<int EPI>
__global__ __launch_bounds__(256) void gemm_k(
    const bf16_t* __restrict__ A, const float* __restrict__ W, const float* __restrict__ bias,
    int K, int N,
    float* __restrict__ outq, bf16_t* __restrict__ outb,
    const float* __restrict__ emb, int gate_h, int gate_e,
    const float* __restrict__ res_h, const float* __restrict__ res_e,
    float* __restrict__ out_h, float* __restrict__ out_e) {
  __shared__ bf16_t As[128 * 64];  // [r][koct swizzled]: idx = r*64 + (k ^ ((r&7)<<3))
  __shared__ bf16_t Bs[128 * 64];  // [n][k swizzled]:    idx = n*64 + (k ^ ((n&7)<<3)), holds W^T tile
  const int m0 = blockIdx.x * 128, n0 = blockIdx.y * 128;
  const int tid = threadIdx.x, wv = tid >> 6, ln = tid & 63;
  const int wr = wv >> 1, wc = wv & 1;
  f32x4 acc[4][4];
  const f32x4 zero = {0.f, 0.f, 0.f, 0.f};
  #pragma unroll
  for (int m = 0; m < 4; ++m)
    #pragma unroll
    for (int n = 0; n < 4; ++n) acc[m][n] = zero;

  for (int k0 = 0; k0 < K; k0 += 64) {
    __syncthreads();
    // A tile: 128x64 bf16 via global_load_lds, source pre-swizzled so linear LDS = swizzled layout
    #pragma unroll
    for (int i = 0; i < 4; ++i) {
      int chunk = wv * 4 + i;
      int slot = chunk * 64 + ln;          // 0..1023, 16B each
      int r = slot >> 3, ks = slot & 7;    // storage octet ks holds logical octet ks^(r&7)
      gld_lds16(A + (size_t)(m0 + r) * K + k0 + ((ks ^ (r & 7)) << 3), &As[chunk * 512]);
    }
    // B tile: W[k0..k0+64][n0..n0+128] f32, transposed+converted into Bs
    #pragma unroll
    for (int i = 0; i < 8; ++i) {
      int task = i * 256 + tid;            // 0..2047
      int kk = task >> 5, nq = (task & 31) << 2;
      f32x4 w4 = *(const f32x4*)(W + (size_t)(k0 + kk) * N + n0 + nq);
      #pragma unroll
      for (int j = 0; j < 4; ++j) {
        int n = nq + j;
        Bs[n * 64 + (kk ^ ((n & 7) << 3))] = (bf16_t)w4[j];
      }
    }
    __syncthreads();
    #pragma unroll
    for (int ks = 0; ks < 2; ++ks) {
      int ko = ks * 4 + (ln >> 4);         // logical k-octet for this lane group
      bf16x8 af[4], bfr[4];
      #pragma unroll
      for (int m = 0; m < 4; ++m) {
        int r = wr * 64 + m * 16 + (ln & 15);
        af[m] = *(const bf16x8*)&As[r * 64 + ((ko ^ (r & 7)) << 3)];
      }
      #pragma unroll
      for (int n = 0; n < 4; ++n) {
        int c = wc * 64 + n * 16 + (ln & 15);
        bfr[n] = *(const bf16x8*)&Bs[c * 64 + ((ko ^ (c & 7)) << 3)];
      }
      #pragma unroll
      for (int m = 0; m < 4; ++m)
        #pragma unroll
        for (int n = 0; n < 4; ++n)
          acc[m][n] = __builtin_amdgcn_mfma_f32_16x16x32_bf16(af[m], bfr[n], acc[m][n], 0, 0, 0);
    }
  }
  // epilogue: D lane map col=ln&15, row=(ln>>4)*4+r
  #pragma unroll
  for (int m = 0; m < 4; ++m) {
    int row = m0 + wr * 64 + m * 16 + ((ln >> 4) << 2);
    #pragma unroll
    for (int n = 0; n < 4; ++n) {
      int col = n0 + wc * 64 + n * 16 + (ln & 15);
      float bv = bias[col];
      #pragma unroll
      for (int r = 0; r < 4; ++r) {
        float val = acc[m][n][r] + bv;
        int rr = row + r;
        if (EPI == 0) {
          int h = col / HD, dd = col - h * HD;
          outq[(size_t)h * SEQ * HD + (size_t)rr * HD + dd] = val;
        } else if (EPI == 1) {
          float z = 0.7978845608028654f * (val + 0.044715f * val * val * val);
          float t = 1.f - 2.f / (__expf(2.f * z) + 1.f);
          outb[(size_t)rr * N + col] = (bf16_t)(0.5f * val * (1.f + t));
        } else {
          if (rr < TENC) {
            out_e[(size_t)rr * D + col] = res_e[(size_t)rr * D + col] + val * emb[gate_e * D + col];
          } else {
            int r2 = rr - TENC;
            out_h[(size_t)r2 * D + col] = res_h[(size_t)r2 * D + col] + val * emb[gate_h * D + col];
          }
        }
      }
    }
  }
}

// ---------------- per-head LN (+RoPE for rows>=128), in place on [h][r][40]; q gets 1/sqrt(40)
__global__ void qk_post(float* __restrict__ qh, float* __restrict__ kh,
                        const float* __restrict__ rc, const float* __restrict__ rs) {
  int r = blockIdx.x * 128 + threadIdx.x;  // 0..1151
  int h = blockIdx.y;
  float cs[HD], sn[HD];
  bool rope = (r >= TENC);
  if (rope) {
    const float* cp = rc + (size_t)(r - TENC) * HD;
    const float* sp = rs + (size_t)(r - TENC) * HD;
    #pragma unroll
    for (int d = 0; d < HD; ++d) { cs[d] = cp[d]; sn[d] = sp[d]; }
  }
  #pragma unroll
  for (int which = 0; which < 2; ++which) {
    float* base = (which == 0 ? qh : kh) + (size_t)h * SEQ * HD + (size_t)r * HD;
    float v[HD], s = 0.f, s2 = 0.f;
    #pragma unroll
    for (int d = 0; d < HD; ++d) { v[d] = base[d]; s += v[d]; }
    float mean = s * (1.f / HD);
    #pragma unroll
    for (int d = 0; d < HD; ++d) { float x = v[d] - mean; v[d] = x; s2 += x * x; }
    float rstd = rsqrtf(s2 * (1.f / HD) + 1e-5f);
    #pragma unroll
    for (int d = 0; d < HD; ++d) v[d] *= rstd;
    if (rope) {
      #pragma unroll
      for (int d = 0; d < HD / 2; ++d) {
        float lo = v[d], hi = v[d + 20];
        v[d]      = lo * cs[d]      - hi * sn[d];
        v[d + 20] = hi * cs[d + 20] + lo * sn[d + 20];
      }
    }
    float qs = (which == 0) ? 0.15811388300841897f : 1.f;  // 1/sqrt(40)
    #pragma unroll
    for (int d = 0; d < HD; ++d) base[d] = v[d] * qs;
  }
}

// ---------------- attention: wave per q-row, online softmax over K tiles of 64
__global__ __launch_bounds__(256) void attn(
    const float* __restrict__ qh, const float* __restrict__ kh,
    const float* __restrict__ vh, bf16_t* __restrict__ obf) {
  const int h = blockIdx.y;
  const int tid = threadIdx.x, wv = tid >> 6, ln = tid & 63;
  const int r = blockIdx.x * 4 + wv;
  __shared__ float ks[64][41];
  __shared__ float vs[64][41];
  const float* kb = kh + (size_t)h * SEQ * HD;
  const float* vb = vh + (size_t)h * SEQ * HD;
  float qreg[HD];
  {
    const float* qp = qh + (size_t)h * SEQ * HD + (size_t)r * HD;
    #pragma unroll
    for (int d = 0; d < HD; ++d) qreg[d] = qp[d];
  }
  const int dl = (ln < HD) ? ln : 0;
  float m = -1e30f, l = 0.f, acc0 = 0.f, acc1 = 0.f;
  for (int jt = 0; jt < SEQ / 64; ++jt) {
    __syncthreads();
    #pragma unroll
    for (int i = 0; i < 10; ++i) {
      int idx = i * 256 + tid;
      int row = idx / HD, dd = idx - row * HD;
      size_t g = (size_t)(jt * 64 + row) * HD + dd;
      ks[row][dd] = kb[g];
      vs[row][dd] = vb[g];
    }
    __syncthreads();
    float s = 0.f;
    #pragma unroll
    for (int d = 0; d < HD; ++d) s = fmaf(qreg[d], ks[ln][d], s);
    float mt = s;
    #pragma unroll
    for (int o = 32; o > 0; o >>= 1) mt = fmaxf(mt, __shfl_xor(mt, o));
    float mnew = fmaxf(m, mt);
    float scl = __expf(m - mnew);
    float p = __expf(s - mnew);
    l = l * scl + p;
    acc0 *= scl; acc1 *= scl;
    m = mnew;
    #pragma unroll
    for (int j = 0; j < 64; j += 2) {
      acc0 = fmaf(__shfl(p, j),     vs[j][dl],     acc0);
      acc1 = fmaf(__shfl(p, j + 1), vs[j + 1][dl], acc1);
    }
  }
  float lt = l;
  #pragma unroll
  for (int o = 32; o > 0; o >>= 1) lt += __shfl_xor(lt, o);
  if (ln < HD) obf[(size_t)r * D + h * HD + ln] = (bf16_t)((acc0 + acc1) / lt);
}

extern "C" void kernel_launch(void* const* d_in, const int* in_sizes, int n_in,
                              void* d_out, int out_size, void* d_ws, size_t ws_size,
                              hipStream_t stream) {
  const float* hid = (const float*)d_in[0];
  const float* enc = (const float*)d_in[1];
  const float* tem = (const float*)d_in[2];
  const float* rc  = (const float*)d_in[3];
  const float* rs  = (const float*)d_in[4];
  const float* aw  = (const float*)d_in[5];
  const float* ab  = (const float*)d_in[6];
  const float* wq  = (const float*)d_in[7];
  const float* bq  = (const float*)d_in[8];
  const float* wk  = (const float*)d_in[9];
  const float* bk  = (const float*)d_in[10];
  const float* wvv = (const float*)d_in[11];
  const float* bv  = (const float*)d_in[12];
  const float* wo  = (const float*)d_in[13];
  const float* bo  = (const float*)d_in[14];
  const float* w1  = (const float*)d_in[15];
  const float* b1  = (const float*)d_in[16];
  const float* w2  = (const float*)d_in[17];
  const float* b2  = (const float*)d_in[18];
  float* out_hid = (float*)d_out;
  float* out_enc = out_hid + (size_t)THID * D;

  char* ws = (char*)d_ws;
  size_t off = 0;
  auto alloc = [&](size_t b) { char* p = ws + off; off += (b + 255) & ~(size_t)255; return p; };
  float*  emb = (float*) alloc((size_t)12 * D * 4);          // 0.12 MB
  bf16_t* xln = (bf16_t*)alloc((size_t)SEQ * D * 2);         // 5.9 MB; reused for attn-out bf16
  float*  qh  = (float*) alloc((size_t)NH * SEQ * HD * 4);   // 11.8 MB; qh+kh reused for FF act
  float*  kh  = (float*) alloc((size_t)NH * SEQ * HD * 4);
  float*  vh  = (float*) alloc((size_t)NH * SEQ * HD * 4);
  float*  h1  = (float*) alloc((size_t)THID * D * 4);        // 10.5 MB
  float*  e1  = (float*) alloc((size_t)TENC * D * 4);        // 1.3 MB
  bf16_t* obf = xln;        // attn output (written after xln last read, read before x2 written)
  bf16_t* aff = (bf16_t*)qh;  // FF1 activation 23.6 MB = qh+kh (dead after attn)

  ada_gemv<<<dim3(240), dim3(128), 0, stream>>>(tem, aw, ab, emb);
  ln_mod<<<dim3(SEQ), dim3(256), 0, stream>>>(hid, enc, emb, xln, 0, 2, 1, 3);
  gemm_k<0><<<dim3(9, 20), dim3(256), 0, stream>>>(xln, wq, bq, D, D, qh, nullptr,
      nullptr, 0, 0, nullptr, nullptr, nullptr, nullptr);
  gemm_k<0><<<dim3(9, 20), dim3(256), 0, stream>>>(xln, wk, bk, D, D, kh, nullptr,
      nullptr, 0, 0, nullptr, nullptr, nullptr, nullptr);
  gemm_k<0><<<dim3(9, 20), dim3(256), 0, stream>>>(xln, wvv, bv, D, D, vh, nullptr,
      nullptr, 0, 0, nullptr, nullptr, nullptr, nullptr);
  qk_post<<<dim3(9, 64), dim3(128), 0, stream>>>(qh, kh, rc, rs);
  attn<<<dim3(288, 64), dim3(256), 0, stream>>>(qh, kh, vh, obf);
  gemm_k<2><<<dim3(9, 20), dim3(256), 0, stream>>>(obf, wo, bo, D, D, nullptr, nullptr,
      emb, 4, 5, hid, enc, h1, e1);
  ln_mod<<<dim3(SEQ), dim3(256), 0, stream>>>(h1, e1, emb, xln, 6, 8, 7, 9);
  gemm_k<1><<<dim3(9, 80), dim3(256), 0, stream>>>(xln, w1, b1, D, FFD, nullptr, aff,
      nullptr, 0, 0, nullptr, nullptr, nullptr, nullptr);
  gemm_k<2><<<dim3(9, 20), dim3(256), 0, stream>>>(aff, w2, b2, FFD, D, nullptr, nullptr,
      emb, 10, 11, h1, e1, out_hid, out_enc);
}

// Round 2
// 1635.054 us; speedup vs baseline: 2.0518x; 2.0518x over previous
//
#include <hip/hip_runtime.h>
#include <stdint.h>

#define D 2560
#define NH 64
#define HD 40
#define TE_ 512
#define FFD 10240
#define TENC 128
#define THID 1024
#define SEQ 1152   // TENC + THID

typedef __bf16 bf16_t;
typedef __bf16 bf16x8 __attribute__((ext_vector_type(8)));
typedef float  f32x4  __attribute__((ext_vector_type(4)));

__device__ __forceinline__ void gld_lds16(const void* g, void* l) {
  __builtin_amdgcn_global_load_lds((__attribute__((address_space(1))) void*)(g),
                                   (__attribute__((address_space(3))) void*)(l), 16, 0, 0);
}

// ---------------- ada: emb = time_embed @ ada_w + ada_b  (1x512 @ 512x30720)
__global__ void ada_gemv(const float* __restrict__ te, const float* __restrict__ aw,
                         const float* __restrict__ ab, float* __restrict__ emb) {
  int j = blockIdx.x * 128 + threadIdx.x;
  float acc = ab[j];
  #pragma unroll 8
  for (int k = 0; k < TE_; ++k) acc = fmaf(te[k], aw[(size_t)k * (12 * D) + j], acc);
  emb[j] = acc;
}

// ---------------- LN + adaLN modulation -> bf16 x  (rows 0..127 = encoder)
__global__ void ln_mod(const float* __restrict__ hid, const float* __restrict__ enc,
                       const float* __restrict__ emb, bf16_t* __restrict__ out,
                       int shift_h, int scale_h, int shift_e, int scale_e) {
  int row = blockIdx.x, tid = threadIdx.x;
  const float *src, *sc, *sh;
  if (row < TENC) { src = enc + (size_t)row * D;          sc = emb + scale_e * D; sh = emb + shift_e * D; }
  else            { src = hid + (size_t)(row - TENC) * D; sc = emb + scale_h * D; sh = emb + shift_h * D; }
  float v[10], s = 0.f, s2 = 0.f;
  #pragma unroll
  for (int i = 0; i < 10; ++i) { v[i] = src[tid + i * 256]; s += v[i]; s2 += v[i] * v[i]; }
  #pragma unroll
  for (int o = 32; o > 0; o >>= 1) { s += __shfl_down(s, o); s2 += __shfl_down(s2, o); }
  __shared__ float red[8];
  int wv = tid >> 6, ln = tid & 63;
  if (ln == 0) { red[wv] = s; red[4 + wv] = s2; }
  __syncthreads();
  s  = red[0] + red[1] + red[2] + red[3];
  s2 = red[4] + red[5] + red[6] + red[7];
  float mean = s * (1.f / D);
  float rstd = rsqrtf(s2 * (1.f / D) - mean * mean + 1e-5f);
  #pragma unroll
  for (int i = 0; i < 10; ++i) {
    int c = tid + i * 256;
    out[(size_t)row * D + c] = (bf16_t)((v[i] - mean) * rstd * (1.f + sc[c]) + sh[c]);
  }
}

// ---------------- GEMM: C[M=1152][N] = A_bf16[M][K] @ W_f32[K][N] + bias, fused epilogues
// EPI 0: scatter to head layout [h][row][d] f32 (Q,K)
// EPI 1: gelu(tanh) -> bf16 row-major (FF1)
// EPI 2: residual + gate -> f32 (O-proj -> h1/e1, FF2 -> d_out)
// EPI 3: V^T bf16 [h][48][SEQ] for attention B-operand
template<int EPI>
__global__ __launch_bounds__(256) void gemm_k(
    const bf16_t* __restrict__ A, const float* __restrict__ W, const float* __restrict__ bias,
    int K, int N,
    float* __restrict__ outq, bf16_t* __restrict__ outb,
    const float* __restrict__ emb, int gate_h, int gate_e,
    const float* __restrict__ res_h, const float* __restrict__ res_e,
    float* __restrict__ out_h, float* __restrict__ out_e) {
  __shared__ bf16_t As[128 * 64];  // [r][koct swizzled]: idx = r*64 + (k ^ ((r&7)<<3))
  __shared__ bf16_t Bs[128 * 64];  // [n][k swizzled]:    idx = n*64 + (k ^ ((n&7)<<3)), holds W^T tile
  const int m0 = blockIdx.x * 128, n0 = blockIdx.y * 128;
  const int tid = threadIdx.x, wv = tid >> 6, ln = tid & 63;
  const int wr = wv >> 1, wc = wv & 1;
  f32x4 acc[4][4];
  const f32x4 zero = {0.f, 0.f, 0.f, 0.f};
  #pragma unroll
  for (int m = 0; m < 4; ++m)
    #pragma unroll
    for (int n = 0; n < 4; ++n) acc[m][n] = zero;

  for (int k0 = 0; k0 < K; k0 += 64) {
    __syncthreads();
    #pragma unroll
    for (int i = 0; i < 4; ++i) {
      int chunk = wv * 4 + i;
      int slot = chunk * 64 + ln;          // 0..1023, 16B each
      int r = slot >> 3, ks = slot & 7;    // storage octet ks holds logical octet ks^(r&7)
      gld_lds16(A + (size_t)(m0 + r) * K + k0 + ((ks ^ (r & 7)) << 3), &As[chunk * 512]);
    }
    #pragma unroll
    for (int i = 0; i < 8; ++i) {
      int task = i * 256 + tid;            // 0..2047
      int kk = task >> 5, nq = (task & 31) << 2;
      f32x4 w4 = *(const f32x4*)(W + (size_t)(k0 + kk) * N + n0 + nq);
      #pragma unroll
      for (int j = 0; j < 4; ++j) {
        int n = nq + j;
        Bs[n * 64 + (kk ^ ((n & 7) << 3))] = (bf16_t)w4[j];
      }
    }
    __syncthreads();
    #pragma unroll
    for (int ks = 0; ks < 2; ++ks) {
      int ko = ks * 4 + (ln >> 4);
      bf16x8 af[4], bfr[4];
      #pragma unroll
      for (int m = 0; m < 4; ++m) {
        int r = wr * 64 + m * 16 + (ln & 15);
        af[m] = *(const bf16x8*)&As[r * 64 + ((ko ^ (r & 7)) << 3)];
      }
      #pragma unroll
      for (int n = 0; n < 4; ++n) {
        int c = wc * 64 + n * 16 + (ln & 15);
        bfr[n] = *(const bf16x8*)&Bs[c * 64 + ((ko ^ (c & 7)) << 3)];
      }
      #pragma unroll
      for (int m = 0; m < 4; ++m)
        #pragma unroll
        for (int n = 0; n < 4; ++n)
          acc[m][n] = __builtin_amdgcn_mfma_f32_16x16x32_bf16(af[m], bfr[n], acc[m][n], 0, 0, 0);
    }
  }
  // epilogue: D lane map col=ln&15, row=(ln>>4)*4+r
  #pragma unroll
  for (int m = 0; m < 4; ++m) {
    int row = m0 + wr * 64 + m * 16 + ((ln >> 4) << 2);
    #pragma unroll
    for (int n = 0; n < 4; ++n) {
      int col = n0 + wc * 64 + n * 16 + (ln & 15);
      float bv = bias[col];
      #pragma unroll
      for (int r = 0; r < 4; ++r) {
        float val = acc[m][n][r] + bv;
        int rr = row + r;
        if (EPI == 0) {
          int h = col / HD, dd = col - h * HD;
          outq[(size_t)h * SEQ * HD + (size_t)rr * HD + dd] = val;
        } else if (EPI == 1) {
          float z = 0.7978845608028654f * (val + 0.044715f * val * val * val);
          float t = 1.f - 2.f / (__expf(2.f * z) + 1.f);
          outb[(size_t)rr * N + col] = (bf16_t)(0.5f * val * (1.f + t));
        } else if (EPI == 3) {
          int h = col / HD, dd = col - h * HD;
          outb[((size_t)h * 48 + dd) * SEQ + rr] = (bf16_t)val;
        } else {
          if (rr < TENC) {
            out_e[(size_t)rr * D + col] = res_e[(size_t)rr * D + col] + val * emb[gate_e * D + col];
          } else {
            int r2 = rr - TENC;
            out_h[(size_t)r2 * D + col] = res_h[(size_t)r2 * D + col] + val * emb[gate_h * D + col];
          }
        }
      }
    }
  }
}

// ---------------- per-head LN (+RoPE rows>=128); f32 [h][r][40] -> bf16 [h][r][64] zero-padded
__global__ void qk_post(const float* __restrict__ qh, const float* __restrict__ kh,
                        const float* __restrict__ rc, const float* __restrict__ rs,
                        bf16_t* __restrict__ qb, bf16_t* __restrict__ kb) {
  int r = blockIdx.x * 128 + threadIdx.x;  // 0..1151
  int h = blockIdx.y;
  float cs[HD], sn[HD];
  bool rope = (r >= TENC);
  if (rope) {
    const float* cp = rc + (size_t)(r - TENC) * HD;
    const float* sp = rs + (size_t)(r - TENC) * HD;
    #pragma unroll
    for (int d = 0; d < HD; ++d) { cs[d] = cp[d]; sn[d] = sp[d]; }
  }
  #pragma unroll
  for (int which = 0; which < 2; ++which) {
    const float* base = (which == 0 ? qh : kh) + (size_t)h * SEQ * HD + (size_t)r * HD;
    bf16_t* dst = (which == 0 ? qb : kb) + ((size_t)h * SEQ + r) * 64;
    float v[HD], s = 0.f, s2 = 0.f;
    #pragma unroll
    for (int d = 0; d < HD; ++d) { v[d] = base[d]; s += v[d]; }
    float mean = s * (1.f / HD);
    #pragma unroll
    for (int d = 0; d < HD; ++d) { float x = v[d] - mean; v[d] = x; s2 += x * x; }
    float rstd = rsqrtf(s2 * (1.f / HD) + 1e-5f);
    #pragma unroll
    for (int d = 0; d < HD; ++d) v[d] *= rstd;
    if (rope) {
      #pragma unroll
      for (int d = 0; d < HD / 2; ++d) {
        float lo = v[d], hi = v[d + 20];
        v[d]      = lo * cs[d]      - hi * sn[d];
        v[d + 20] = hi * cs[d + 20] + lo * sn[d + 20];
      }
    }
    float qs = (which == 0) ? 0.15811388300841897f : 1.f;  // 1/sqrt(40)
    #pragma unroll
    for (int d = 0; d < HD; ++d) dst[d] = (bf16_t)(v[d] * qs);
    #pragma unroll
    for (int d = HD; d < 64; ++d) dst[d] = (bf16_t)0.f;
  }
}

// ---------------- MFMA flash attention: block = (64 q-rows, head), 4 waves x 16 q-rows
__global__ __launch_bounds__(256) void attn_mfma(
    const bf16_t* __restrict__ qb, const bf16_t* __restrict__ kb,
    const bf16_t* __restrict__ vt, bf16_t* __restrict__ obf) {
  __shared__ bf16_t Ks[64 * 64];      // [kv][d oct swizzled by kv&7]
  __shared__ bf16_t Vs[48 * 64];      // [d][kv oct swizzled by d&7]
  __shared__ bf16_t Ps[4][16 * 64];   // per-wave [q][kv oct swizzled by q&7]
  const int h = blockIdx.y;
  const int tid = threadIdx.x, wv = tid >> 6, ln = tid & 63;
  const int qbase = blockIdx.x * 64 + wv * 16;
  const int lr = ln & 15, lg = ln >> 4;

  bf16x8 af[2];
  {
    const bf16_t* qp = qb + ((size_t)h * SEQ + qbase + lr) * 64 + lg * 8;
    af[0] = *(const bf16x8*)(qp);
    af[1] = *(const bf16x8*)(qp + 32);
  }
  const f32x4 zero = {0.f, 0.f, 0.f, 0.f};
  f32x4 acc[3];
  acc[0] = zero; acc[1] = zero; acc[2] = zero;
  float mrow[4], lrow[4];
  #pragma unroll
  for (int r = 0; r < 4; ++r) { mrow[r] = -1e30f; lrow[r] = 0.f; }

  const bf16_t* kbh = kb + (size_t)h * SEQ * 64;
  const bf16_t* vth = vt + (size_t)h * 48 * SEQ;

  for (int kv0 = 0; kv0 < SEQ; kv0 += 64) {
    __syncthreads();
    #pragma unroll
    for (int i = 0; i < 2; ++i) {           // K tile: 8 groups of 64 x 16B
      int g = wv * 2 + i;
      int slot = g * 64 + ln;
      int kr = slot >> 3, so = slot & 7;
      gld_lds16(kbh + (size_t)(kv0 + kr) * 64 + ((so ^ (kr & 7)) << 3), &Ks[g * 512]);
    }
    #pragma unroll
    for (int i = 0; i < 2; ++i) {           // V^T tile: 6 groups
      int g = wv + 4 * i;
      if (g < 6) {
        int slot = g * 64 + ln;
        int dr = slot >> 3, so = slot & 7;
        gld_lds16(vth + (size_t)dr * SEQ + kv0 + ((so ^ (dr & 7)) << 3), &Vs[g * 512]);
      }
    }
    __syncthreads();
    // QK^T: 16 q x 64 kv
    f32x4 s[4];
    #pragma unroll
    for (int nt = 0; nt < 4; ++nt) {
      s[nt] = zero;
      int kvr = nt * 16 + lr;
      #pragma unroll
      for (int kh = 0; kh < 2; ++kh) {
        bf16x8 bk = *(const bf16x8*)&Ks[kvr * 64 + (((kh * 4 + lg) ^ (kvr & 7)) << 3)];
        s[nt] = __builtin_amdgcn_mfma_f32_16x16x32_bf16(af[kh], bk, s[nt], 0, 0, 0);
      }
    }
    // online softmax (rows distributed: q = lg*4 + r, kv across lr + nt)
    float pn[4][4];
    #pragma unroll
    for (int r = 0; r < 4; ++r) {
      float tm = fmaxf(fmaxf(s[0][r], s[1][r]), fmaxf(s[2][r], s[3][r]));
      #pragma unroll
      for (int o = 8; o > 0; o >>= 1) tm = fmaxf(tm, __shfl_xor(tm, o));
      float mn = fmaxf(mrow[r], tm);
      float scl = __expf(mrow[r] - mn);
      mrow[r] = mn;
      float ts = 0.f;
      #pragma unroll
      for (int nt = 0; nt < 4; ++nt) { pn[nt][r] = __expf(s[nt][r] - mn); ts += pn[nt][r]; }
      #pragma unroll
      for (int o = 8; o > 0; o >>= 1) ts += __shfl_xor(ts, o);
      lrow[r] = lrow[r] * scl + ts;
      acc[0][r] *= scl; acc[1][r] *= scl; acc[2][r] *= scl;
    }
    // P -> per-wave LDS (bf16, swizzled)
    #pragma unroll
    for (int nt = 0; nt < 4; ++nt)
      #pragma unroll
      for (int r = 0; r < 4; ++r) {
        int q = lg * 4 + r;
        int kv = nt * 16 + lr;
        Ps[wv][q * 64 + ((((kv >> 3) ^ (q & 7)) << 3) | (kv & 7))] = (bf16_t)pn[nt][r];
      }
    // PV: A = P[16 q][64 kv], B = V[64 kv][16 d] via V^T rows
    bf16x8 pa[2];
    #pragma unroll
    for (int kh = 0; kh < 2; ++kh)
      pa[kh] = *(const bf16x8*)&Ps[wv][lr * 64 + (((kh * 4 + lg) ^ (lr & 7)) << 3)];
    #pragma unroll
    for (int dt = 0; dt < 3; ++dt) {
      #pragma unroll
      for (int kh = 0; kh < 2; ++kh) {
        int dr = dt * 16 + lr;
        bf16x8 bv = *(const bf16x8*)&Vs[dr * 64 + (((kh * 4 + lg) ^ (dr & 7)) << 3)];
        acc[dt] = __builtin_amdgcn_mfma_f32_16x16x32_bf16(pa[kh], bv, acc[dt], 0, 0, 0);
      }
    }
  }
  #pragma unroll
  for (int dt = 0; dt < 3; ++dt) {
    int d = dt * 16 + lr;
    if (d < HD) {
      #pragma unroll
      for (int r = 0; r < 4; ++r) {
        int q = qbase + lg * 4 + r;
        obf[(size_t)q * D + h * HD + d] = (bf16_t)(acc[dt][r] / lrow[r]);
      }
    }
  }
}

extern "C" void kernel_launch(void* const* d_in, const int* in_sizes, int n_in,
                              void* d_out, int out_size, void* d_ws, size_t ws_size,
                              hipStream_t stream) {
  const float* hid = (const float*)d_in[0];
  const float* enc = (const float*)d_in[1];
  const float* tem = (const float*)d_in[2];
  const float* rc  = (const float*)d_in[3];
  const float* rs  = (const float*)d_in[4];
  const float* aw  = (const float*)d_in[5];
  const float* ab  = (const float*)d_in[6];
  const float* wq  = (const float*)d_in[7];
  const float* bq  = (const float*)d_in[8];
  const float* wk  = (const float*)d_in[9];
  const float* bk  = (const float*)d_in[10];
  const float* wvv = (const float*)d_in[11];
  const float* bv  = (const float*)d_in[12];
  const float* wo  = (const float*)d_in[13];
  const float* bo  = (const float*)d_in[14];
  const float* w1  = (const float*)d_in[15];
  const float* b1  = (const float*)d_in[16];
  const float* w2  = (const float*)d_in[17];
  const float* b2  = (const float*)d_in[18];
  float* out_hid = (float*)d_out;
  float* out_enc = out_hid + (size_t)THID * D;

  char* ws = (char*)d_ws;
  size_t off = 0;
  auto alloc = [&](size_t b) { char* p = ws + off; off += (b + 255) & ~(size_t)255; return p; };
  float*  emb = (float*) alloc((size_t)12 * D * 4);          // 0.12 MB
  bf16_t* xln = (bf16_t*)alloc((size_t)SEQ * D * 2);         // 5.9 MB; reused for attn-out bf16
  float*  qh  = (float*) alloc((size_t)NH * SEQ * HD * 4);   // 11.8 MB (f32 Q head layout)
  float*  kh  = (float*) alloc((size_t)NH * SEQ * HD * 4);   // 11.8 MB
  bf16_t* vt  = (bf16_t*)alloc((size_t)NH * 48 * SEQ * 2);   // 7.1 MB (V^T bf16, padded d->48)
  bf16_t* qbb = (bf16_t*)alloc((size_t)NH * SEQ * 64 * 2);   // 9.4 MB (Q bf16 padded)
  bf16_t* kbb = (bf16_t*)alloc((size_t)NH * SEQ * 64 * 2);   // 9.4 MB
  float*  h1  = (float*) alloc((size_t)THID * D * 4);        // 10.5 MB
  float*  e1  = (float*) alloc((size_t)TENC * D * 4);        // 1.3 MB
  bf16_t* obf = xln;          // attn output bf16 (xln dead after QKV gemms)
  bf16_t* aff = (bf16_t*)qh;  // FF1 activation 23.6 MB = qh+kh (dead after attn)

  ada_gemv<<<dim3(240), dim3(128), 0, stream>>>(tem, aw, ab, emb);
  ln_mod<<<dim3(SEQ), dim3(256), 0, stream>>>(hid, enc, emb, xln, 0, 2, 1, 3);
  gemm_k<0><<<dim3(9, 20), dim3(256), 0, stream>>>(xln, wq, bq, D, D, qh, nullptr,
      nullptr, 0, 0, nullptr, nullptr, nullptr, nullptr);
  gemm_k<0><<<dim3(9, 20), dim3(256), 0, stream>>>(xln, wk, bk, D, D, kh, nullptr,
      nullptr, 0, 0, nullptr, nullptr, nullptr, nullptr);
  hipMemsetAsync(vt, 0, (size_t)NH * 48 * SEQ * 2, stream);
  gemm_k<3><<<dim3(9, 20), dim3(256), 0, stream>>>(xln, wvv, bv, D, D, nullptr, vt,
      nullptr, 0, 0, nullptr, nullptr, nullptr, nullptr);
  qk_post<<<dim3(9, 64), dim3(128), 0, stream>>>(qh, kh, rc, rs, qbb, kbb);
  attn_mfma<<<dim3(18, 64), dim3(256), 0, stream>>>(qbb, kbb, vt, obf);
  gemm_k<2><<<dim3(9, 20), dim3(256), 0, stream>>>(obf, wo, bo, D, D, nullptr, nullptr,
      emb, 4, 5, hid, enc, h1, e1);
  ln_mod<<<dim3(SEQ), dim3(256), 0, stream>>>(h1, e1, emb, xln, 6, 8, 7, 9);
  gemm_k<1><<<dim3(9, 80), dim3(256), 0, stream>>>(xln, w1, b1, D, FFD, nullptr, aff,
      nullptr, 0, 0, nullptr, nullptr, nullptr, nullptr);
  gemm_k<2><<<dim3(9, 20), dim3(256), 0, stream>>>(aff, w2, b2, FFD, D, nullptr, nullptr,
      emb, 10, 11, h1, e1, out_hid, out_enc);
}

// Round 3
// 676.391 us; speedup vs baseline: 4.9599x; 2.4173x over previous
//
#include <hip/hip_runtime.h>
#include <stdint.h>

#define D 2560
#define NH 64
#define HD 40
#define TE_ 512
#define FFD 10240
#define TENC 128
#define THID 1024
#define SEQ 1152   // TENC + THID

typedef __bf16 bf16_t;
typedef __bf16 bf16x8 __attribute__((ext_vector_type(8)));
typedef float  f32x4  __attribute__((ext_vector_type(4)));

__device__ __forceinline__ void gld_lds16(const void* g, void* l) {
  __builtin_amdgcn_global_load_lds((__attribute__((address_space(1))) void*)(g),
                                   (__attribute__((address_space(3))) void*)(l), 16, 0, 0);
}

// ---------------- weight transpose+convert: W[K][N] f32 -> Wt[N][K] bf16
__global__ __launch_bounds__(256) void wtrans(const float* __restrict__ W,
                                              bf16_t* __restrict__ Wt, int K, int N) {
  __shared__ float tile[64][65];
  const int bk = blockIdx.x, bn = blockIdx.y, tid = threadIdx.x;
  #pragma unroll
  for (int i = 0; i < 4; ++i) {
    int c = i * 256 + tid;             // 0..1023
    int r = c >> 4, q = c & 15;
    f32x4 v = *(const f32x4*)(W + (size_t)(bk * 64 + r) * N + bn * 64 + q * 4);
    tile[r][q * 4 + 0] = v[0]; tile[r][q * 4 + 1] = v[1];
    tile[r][q * 4 + 2] = v[2]; tile[r][q * 4 + 3] = v[3];
  }
  __syncthreads();
  #pragma unroll
  for (int i = 0; i < 2; ++i) {
    int c = i * 256 + tid;             // 0..511
    int n = c >> 3, kc = c & 7;
    bf16x8 o;
    #pragma unroll
    for (int j = 0; j < 8; ++j) o[j] = (bf16_t)tile[kc * 8 + j][n];
    *(bf16x8*)(Wt + (size_t)(bn * 64 + n) * K + bk * 64 + kc * 8) = o;
  }
}

__global__ void bcat(const float* __restrict__ a, const float* __restrict__ b,
                     const float* __restrict__ c, float* __restrict__ o) {
  int i = blockIdx.x * 256 + threadIdx.x;
  o[i] = i < D ? a[i] : (i < 2 * D ? b[i - D] : c[i - 2 * D]);
}

// ---------------- ada: emb = time_embed @ ada_w + ada_b
__global__ void ada_gemv(const float* __restrict__ te, const float* __restrict__ aw,
                         const float* __restrict__ ab, float* __restrict__ emb) {
  int j = blockIdx.x * 128 + threadIdx.x;
  float acc = ab[j];
  #pragma unroll 8
  for (int k = 0; k < TE_; ++k) acc = fmaf(te[k], aw[(size_t)k * (12 * D) + j], acc);
  emb[j] = acc;
}

// ---------------- LN + adaLN modulation -> bf16 x  (rows 0..127 = encoder)
__global__ void ln_mod(const float* __restrict__ hid, const float* __restrict__ enc,
                       const float* __restrict__ emb, bf16_t* __restrict__ out,
                       int shift_h, int scale_h, int shift_e, int scale_e) {
  int row = blockIdx.x, tid = threadIdx.x;
  const float *src, *sc, *sh;
  if (row < TENC) { src = enc + (size_t)row * D;          sc = emb + scale_e * D; sh = emb + shift_e * D; }
  else            { src = hid + (size_t)(row - TENC) * D; sc = emb + scale_h * D; sh = emb + shift_h * D; }
  float v[10], s = 0.f, s2 = 0.f;
  #pragma unroll
  for (int i = 0; i < 10; ++i) { v[i] = src[tid + i * 256]; s += v[i]; s2 += v[i] * v[i]; }
  #pragma unroll
  for (int o = 32; o > 0; o >>= 1) { s += __shfl_down(s, o); s2 += __shfl_down(s2, o); }
  __shared__ float red[8];
  int wv = tid >> 6, ln = tid & 63;
  if (ln == 0) { red[wv] = s; red[4 + wv] = s2; }
  __syncthreads();
  s  = red[0] + red[1] + red[2] + red[3];
  s2 = red[4] + red[5] + red[6] + red[7];
  float mean = s * (1.f / D);
  float rstd = rsqrtf(s2 * (1.f / D) - mean * mean + 1e-5f);
  #pragma unroll
  for (int i = 0; i < 10; ++i) {
    int c = tid + i * 256;
    out[(size_t)row * D + c] = (bf16_t)((v[i] - mean) * rstd * (1.f + sc[c]) + sh[c]);
  }
}

// ---------------- GEMM v2: C[1152][N] = A_bf16[1152][K] @ Bt_bf16[N][K]^T + bias
// tile 64x128, 4 waves (2x2, each 32x64), BK=64, double-buffered gld_lds16 staging.
// EPI 0: QKV split-scatter (Q,K f32 head layout; V -> V^T bf16 [h][48][SEQ])
// EPI 1: gelu -> bf16 row-major
// EPI 2: residual + gate -> f32
template<int EPI>
__global__ __launch_bounds__(256) void gemm2(
    const bf16_t* __restrict__ A, const bf16_t* __restrict__ Bt,
    const float* __restrict__ bias, int K, int N, int nM,
    float* __restrict__ outq, float* __restrict__ outk, bf16_t* __restrict__ outv,
    bf16_t* __restrict__ outb,
    const float* __restrict__ emb, int gate_h, int gate_e,
    const float* __restrict__ res_h, const float* __restrict__ res_e,
    float* __restrict__ out_h, float* __restrict__ out_e) {
  __shared__ bf16_t As[2][64 * 64];
  __shared__ bf16_t Bs[2][128 * 64];
  const int nwg = gridDim.x;
  const int orig = blockIdx.x;
  const int wg = (orig & 7) * (nwg >> 3) + (orig >> 3);   // XCD-chunked swizzle (nwg%8==0)
  const int bm = wg % nM, bn = wg / nM;
  const int m0 = bm * 64, n0 = bn * 128;
  const int tid = threadIdx.x, wv = tid >> 6, ln = tid & 63;
  const int wr = wv >> 1, wc = wv & 1, lr = ln & 15, lg = ln >> 4;

  f32x4 acc[2][4];
  const f32x4 zero = {0.f, 0.f, 0.f, 0.f};
  #pragma unroll
  for (int m = 0; m < 2; ++m)
    #pragma unroll
    for (int n = 0; n < 4; ++n) acc[m][n] = zero;

  auto stage = [&](int buf, int k0) {
    #pragma unroll
    for (int i = 0; i < 2; ++i) {        // A: 64x64 = 8 chunks
      int g = wv * 2 + i;
      int s = g * 64 + ln;
      int r = s >> 3, ks = s & 7;
      gld_lds16(A + (size_t)(m0 + r) * K + k0 + ((ks ^ (r & 7)) << 3), &As[buf][g * 512]);
    }
    #pragma unroll
    for (int i = 0; i < 4; ++i) {        // Bt: 128x64 = 16 chunks
      int g = wv * 4 + i;
      int s = g * 64 + ln;
      int r = s >> 3, ks = s & 7;
      gld_lds16(Bt + (size_t)(n0 + r) * K + k0 + ((ks ^ (r & 7)) << 3), &Bs[buf][g * 512]);
    }
  };

  const int nt = K >> 6;
  stage(0, 0);
  __syncthreads();
  int cur = 0;
  for (int t = 0; t < nt; ++t) {
    if (t + 1 < nt) stage(cur ^ 1, (t + 1) << 6);
    #pragma unroll
    for (int ks = 0; ks < 2; ++ks) {
      int ko = ks * 4 + lg;
      bf16x8 af[2], bfr[4];
      #pragma unroll
      for (int m = 0; m < 2; ++m) {
        int r = wr * 32 + m * 16 + lr;
        af[m] = *(const bf16x8*)&As[cur][r * 64 + ((ko ^ (r & 7)) << 3)];
      }
      #pragma unroll
      for (int n = 0; n < 4; ++n) {
        int c = wc * 64 + n * 16 + lr;
        bfr[n] = *(const bf16x8*)&Bs[cur][c * 64 + ((ko ^ (c & 7)) << 3)];
      }
      #pragma unroll
      for (int m = 0; m < 2; ++m)
        #pragma unroll
        for (int n = 0; n < 4; ++n)
          acc[m][n] = __builtin_amdgcn_mfma_f32_16x16x32_bf16(af[m], bfr[n], acc[m][n], 0, 0, 0);
    }
    __syncthreads();       // drains vmcnt (next buffer staged) + lgkm
    cur ^= 1;
  }

  #pragma unroll
  for (int m = 0; m < 2; ++m) {
    int row = m0 + wr * 32 + m * 16 + (lg << 2);
    #pragma unroll
    for (int n = 0; n < 4; ++n) {
      int col = n0 + wc * 64 + n * 16 + lr;
      float bv = bias[col];
      #pragma unroll
      for (int r = 0; r < 4; ++r) {
        float val = acc[m][n][r] + bv;
        int rr = row + r;
        if (EPI == 0) {
          int which = col / D, cc = col - which * D;
          int h = cc / HD, dd = cc - h * HD;
          if (which == 0)      outq[(size_t)h * SEQ * HD + (size_t)rr * HD + dd] = val;
          else if (which == 1) outk[(size_t)h * SEQ * HD + (size_t)rr * HD + dd] = val;
          else                 outv[((size_t)h * 48 + dd) * SEQ + rr] = (bf16_t)val;
        } else if (EPI == 1) {
          float z = 0.7978845608028654f * (val + 0.044715f * val * val * val);
          float t = 1.f - 2.f / (__expf(2.f * z) + 1.f);
          outb[(size_t)rr * N + col] = (bf16_t)(0.5f * val * (1.f + t));
        } else {
          if (rr < TENC) {
            out_e[(size_t)rr * D + col] = res_e[(size_t)rr * D + col] + val * emb[gate_e * D + col];
          } else {
            int r2 = rr - TENC;
            out_h[(size_t)r2 * D + col] = res_h[(size_t)r2 * D + col] + val * emb[gate_h * D + col];
          }
        }
      }
    }
  }
}

// ---------------- per-head LN (+RoPE rows>=128); f32 [h][r][40] -> bf16 [h][r][64] zero-padded
__global__ void qk_post(const float* __restrict__ qh, const float* __restrict__ kh,
                        const float* __restrict__ rc, const float* __restrict__ rs,
                        bf16_t* __restrict__ qb, bf16_t* __restrict__ kb) {
  int r = blockIdx.x * 128 + threadIdx.x;  // 0..1151
  int h = blockIdx.y;
  float cs[HD], sn[HD];
  bool rope = (r >= TENC);
  if (rope) {
    const float* cp = rc + (size_t)(r - TENC) * HD;
    const float* sp = rs + (size_t)(r - TENC) * HD;
    #pragma unroll
    for (int d = 0; d < HD; ++d) { cs[d] = cp[d]; sn[d] = sp[d]; }
  }
  #pragma unroll
  for (int which = 0; which < 2; ++which) {
    const float* base = (which == 0 ? qh : kh) + (size_t)h * SEQ * HD + (size_t)r * HD;
    bf16_t* dst = (which == 0 ? qb : kb) + ((size_t)h * SEQ + r) * 64;
    float v[HD], s = 0.f, s2 = 0.f;
    #pragma unroll
    for (int d = 0; d < HD; ++d) { v[d] = base[d]; s += v[d]; }
    float mean = s * (1.f / HD);
    #pragma unroll
    for (int d = 0; d < HD; ++d) { float x = v[d] - mean; v[d] = x; s2 += x * x; }
    float rstd = rsqrtf(s2 * (1.f / HD) + 1e-5f);
    #pragma unroll
    for (int d = 0; d < HD; ++d) v[d] *= rstd;
    if (rope) {
      #pragma unroll
      for (int d = 0; d < HD / 2; ++d) {
        float lo = v[d], hi = v[d + 20];
        v[d]      = lo * cs[d]      - hi * sn[d];
        v[d + 20] = hi * cs[d + 20] + lo * sn[d + 20];
      }
    }
    float qs = (which == 0) ? 0.15811388300841897f : 1.f;  // 1/sqrt(40)
    #pragma unroll
    for (int d = 0; d < HD; ++d) dst[d] = (bf16_t)(v[d] * qs);
    #pragma unroll
    for (int d = HD; d < 64; ++d) dst[d] = (bf16_t)0.f;
  }
}

// ---------------- MFMA flash attention: block = (64 q-rows, head), 4 waves x 16 q-rows
__global__ __launch_bounds__(256) void attn_mfma(
    const bf16_t* __restrict__ qb, const bf16_t* __restrict__ kb,
    const bf16_t* __restrict__ vt, bf16_t* __restrict__ obf) {
  __shared__ bf16_t Ks[64 * 64];
  __shared__ bf16_t Vs[48 * 64];
  __shared__ bf16_t Ps[4][16 * 64];
  const int h = blockIdx.y;
  const int tid = threadIdx.x, wv = tid >> 6, ln = tid & 63;
  const int qbase = blockIdx.x * 64 + wv * 16;
  const int lr = ln & 15, lg = ln >> 4;

  bf16x8 af[2];
  {
    const bf16_t* qp = qb + ((size_t)h * SEQ + qbase + lr) * 64 + lg * 8;
    af[0] = *(const bf16x8*)(qp);
    af[1] = *(const bf16x8*)(qp + 32);
  }
  const f32x4 zero = {0.f, 0.f, 0.f, 0.f};
  f32x4 acc[3];
  acc[0] = zero; acc[1] = zero; acc[2] = zero;
  float mrow[4], lrow[4];
  #pragma unroll
  for (int r = 0; r < 4; ++r) { mrow[r] = -1e30f; lrow[r] = 0.f; }

  const bf16_t* kbh = kb + (size_t)h * SEQ * 64;
  const bf16_t* vth = vt + (size_t)h * 48 * SEQ;

  for (int kv0 = 0; kv0 < SEQ; kv0 += 64) {
    __syncthreads();
    #pragma unroll
    for (int i = 0; i < 2; ++i) {
      int g = wv * 2 + i;
      int slot = g * 64 + ln;
      int kr = slot >> 3, so = slot & 7;
      gld_lds16(kbh + (size_t)(kv0 + kr) * 64 + ((so ^ (kr & 7)) << 3), &Ks[g * 512]);
    }
    #pragma unroll
    for (int i = 0; i < 2; ++i) {
      int g = wv + 4 * i;
      if (g < 6) {
        int slot = g * 64 + ln;
        int dr = slot >> 3, so = slot & 7;
        gld_lds16(vth + (size_t)dr * SEQ + kv0 + ((so ^ (dr & 7)) << 3), &Vs[g * 512]);
      }
    }
    __syncthreads();
    f32x4 s[4];
    #pragma unroll
    for (int nt = 0; nt < 4; ++nt) {
      s[nt] = zero;
      int kvr = nt * 16 + lr;
      #pragma unroll
      for (int kk = 0; kk < 2; ++kk) {
        bf16x8 bk = *(const bf16x8*)&Ks[kvr * 64 + (((kk * 4 + lg) ^ (kvr & 7)) << 3)];
        s[nt] = __builtin_amdgcn_mfma_f32_16x16x32_bf16(af[kk], bk, s[nt], 0, 0, 0);
      }
    }
    float pn[4][4];
    #pragma unroll
    for (int r = 0; r < 4; ++r) {
      float tm = fmaxf(fmaxf(s[0][r], s[1][r]), fmaxf(s[2][r], s[3][r]));
      #pragma unroll
      for (int o = 8; o > 0; o >>= 1) tm = fmaxf(tm, __shfl_xor(tm, o));
      float mn = fmaxf(mrow[r], tm);
      float scl = __expf(mrow[r] - mn);
      mrow[r] = mn;
      float ts = 0.f;
      #pragma unroll
      for (int nt = 0; nt < 4; ++nt) { pn[nt][r] = __expf(s[nt][r] - mn); ts += pn[nt][r]; }
      #pragma unroll
      for (int o = 8; o > 0; o >>= 1) ts += __shfl_xor(ts, o);
      lrow[r] = lrow[r] * scl + ts;
      acc[0][r] *= scl; acc[1][r] *= scl; acc[2][r] *= scl;
    }
    #pragma unroll
    for (int nt = 0; nt < 4; ++nt)
      #pragma unroll
      for (int r = 0; r < 4; ++r) {
        int q = lg * 4 + r;
        int kv = nt * 16 + lr;
        Ps[wv][q * 64 + ((((kv >> 3) ^ (q & 7)) << 3) | (kv & 7))] = (bf16_t)pn[nt][r];
      }
    bf16x8 pa[2];
    #pragma unroll
    for (int kk = 0; kk < 2; ++kk)
      pa[kk] = *(const bf16x8*)&Ps[wv][lr * 64 + (((kk * 4 + lg) ^ (lr & 7)) << 3)];
    #pragma unroll
    for (int dt = 0; dt < 3; ++dt) {
      #pragma unroll
      for (int kk = 0; kk < 2; ++kk) {
        int dr = dt * 16 + lr;
        bf16x8 bv = *(const bf16x8*)&Vs[dr * 64 + (((kk * 4 + lg) ^ (dr & 7)) << 3)];
        acc[dt] = __builtin_amdgcn_mfma_f32_16x16x32_bf16(pa[kk], bv, acc[dt], 0, 0, 0);
      }
    }
  }
  #pragma unroll
  for (int dt = 0; dt < 3; ++dt) {
    int d = dt * 16 + lr;
    if (d < HD) {
      #pragma unroll
      for (int r = 0; r < 4; ++r) {
        int q = qbase + lg * 4 + r;
        obf[(size_t)q * D + h * HD + d] = (bf16_t)(acc[dt][r] / lrow[r]);
      }
    }
  }
}

extern "C" void kernel_launch(void* const* d_in, const int* in_sizes, int n_in,
                              void* d_out, int out_size, void* d_ws, size_t ws_size,
                              hipStream_t stream) {
  const float* hid = (const float*)d_in[0];
  const float* enc = (const float*)d_in[1];
  const float* tem = (const float*)d_in[2];
  const float* rc  = (const float*)d_in[3];
  const float* rs  = (const float*)d_in[4];
  const float* aw  = (const float*)d_in[5];
  const float* ab  = (const float*)d_in[6];
  const float* wq  = (const float*)d_in[7];
  const float* bq  = (const float*)d_in[8];
  const float* wk  = (const float*)d_in[9];
  const float* bk  = (const float*)d_in[10];
  const float* wvv = (const float*)d_in[11];
  const float* bv  = (const float*)d_in[12];
  const float* wo  = (const float*)d_in[13];
  const float* bo  = (const float*)d_in[14];
  const float* w1  = (const float*)d_in[15];
  const float* b1  = (const float*)d_in[16];
  const float* w2  = (const float*)d_in[17];
  const float* b2  = (const float*)d_in[18];
  float* out_hid = (float*)d_out;
  float* out_enc = out_hid + (size_t)THID * D;

  char* ws = (char*)d_ws;
  size_t off = 0;
  auto alloc = [&](size_t b) { char* p = ws + off; off += (b + 255) & ~(size_t)255; return p; };
  float*  emb  = (float*) alloc((size_t)12 * D * 4);
  bf16_t* xln  = (bf16_t*)alloc((size_t)SEQ * D * 2);          // also attn-out bf16
  float*  qh   = (float*) alloc((size_t)NH * SEQ * HD * 4);    // f32 Q head layout; +kh = FF1 act
  float*  kh   = (float*) alloc((size_t)NH * SEQ * HD * 4);
  bf16_t* vt   = (bf16_t*)alloc((size_t)NH * 48 * SEQ * 2);    // V^T bf16, d padded to 48
  bf16_t* qbb  = (bf16_t*)alloc((size_t)NH * SEQ * 64 * 2);    // Q bf16 padded; +kbb = h1/e1 after attn
  bf16_t* kbb  = (bf16_t*)alloc((size_t)NH * SEQ * 64 * 2);
  bf16_t* wqkvT= (bf16_t*)alloc((size_t)3 * D * D * 2);        // [7680][2560]
  bf16_t* woT  = (bf16_t*)alloc((size_t)D * D * 2);
  bf16_t* w1T  = (bf16_t*)alloc((size_t)FFD * D * 2);          // [10240][2560]
  bf16_t* w2T  = (bf16_t*)alloc((size_t)D * FFD * 2);          // [2560][10240]
  float*  bqkv = (float*) alloc((size_t)3 * D * 4);
  bf16_t* obf = xln;
  bf16_t* aff = (bf16_t*)qh;          // FF1 activation (qh+kh dead after qk_post)
  float*  h1  = (float*)qbb;          // residual-1 hid (qbb/kbb dead after attn)
  float*  e1  = h1 + (size_t)THID * D;

  // weight prep (bf16 + transpose)
  wtrans<<<dim3(40, 40), dim3(256), 0, stream>>>(wq,  wqkvT,                    D, D);
  wtrans<<<dim3(40, 40), dim3(256), 0, stream>>>(wk,  wqkvT + (size_t)D * D,    D, D);
  wtrans<<<dim3(40, 40), dim3(256), 0, stream>>>(wvv, wqkvT + (size_t)2 * D * D,D, D);
  wtrans<<<dim3(40, 40), dim3(256), 0, stream>>>(wo,  woT,                      D, D);
  wtrans<<<dim3(40, 160), dim3(256), 0, stream>>>(w1, w1T, D, FFD);
  wtrans<<<dim3(160, 40), dim3(256), 0, stream>>>(w2, w2T, FFD, D);
  bcat<<<dim3(30), dim3(256), 0, stream>>>(bq, bk, bv, bqkv);

  ada_gemv<<<dim3(240), dim3(128), 0, stream>>>(tem, aw, ab, emb);
  ln_mod<<<dim3(SEQ), dim3(256), 0, stream>>>(hid, enc, emb, xln, 0, 2, 1, 3);
  hipMemsetAsync(vt, 0, (size_t)NH * 48 * SEQ * 2, stream);
  // QKV fused: N=7680, grid 18*60=1080
  gemm2<0><<<dim3(18 * 60), dim3(256), 0, stream>>>(xln, wqkvT, bqkv, D, 3 * D, 18,
      qh, kh, vt, nullptr, nullptr, 0, 0, nullptr, nullptr, nullptr, nullptr);
  qk_post<<<dim3(9, 64), dim3(128), 0, stream>>>(qh, kh, rc, rs, qbb, kbb);
  attn_mfma<<<dim3(18, 64), dim3(256), 0, stream>>>(qbb, kbb, vt, obf);
  // O-proj: grid 18*20=360
  gemm2<2><<<dim3(18 * 20), dim3(256), 0, stream>>>(obf, woT, bo, D, D, 18,
      nullptr, nullptr, nullptr, nullptr, emb, 4, 5, hid, enc, h1, e1);
  ln_mod<<<dim3(SEQ), dim3(256), 0, stream>>>(h1, e1, emb, xln, 6, 8, 7, 9);
  // FF1: grid 18*80=1440
  gemm2<1><<<dim3(18 * 80), dim3(256), 0, stream>>>(xln, w1T, b1, D, FFD, 18,
      nullptr, nullptr, nullptr, aff, nullptr, 0, 0, nullptr, nullptr, nullptr, nullptr);
  // FF2: grid 360
  gemm2<2><<<dim3(18 * 20), dim3(256), 0, stream>>>(aff, w2T, b2, FFD, D, 18,
      nullptr, nullptr, nullptr, nullptr, emb, 10, 11, h1, e1, out_hid, out_enc);
}